// Round 8
// baseline (187.008 us; speedup 1.0000x reference)
//
#include <hip/hip_runtime.h>
#include <cmath>

#define B_ 16384
#define S_ 512
#define P_ 1024
#define K_ 8
#define D_ 64
#define H_ 128
#define BT 8     // batch rows per block; bf16-packed tile = 512*4*4B = 8 KB

// float -> bf16 (RNE, finite inputs) packed helpers
static __device__ __forceinline__ unsigned int rne16(float f) {
  unsigned int u = __float_as_uint(f);
  return (u + 0x7fffu + ((u >> 16) & 1u)) >> 16;
}
static __device__ __forceinline__ float bflo(unsigned int u) { return __uint_as_float(u << 16); }
static __device__ __forceinline__ float bfhi(unsigned int u) { return __uint_as_float(u & 0xffff0000u); }

// ---------------- Kernel A: sklproj[s][h] = dot(skl_emd[s,:], U[h,:]) ----------------
__global__ __launch_bounds__(128) void proj_skl_kernel(
    const float* __restrict__ skl_emd, const float* __restrict__ U,
    float* __restrict__ sklproj) {
  __shared__ float row[D_];
  const int s = blockIdx.x, h = threadIdx.x;
  if (h < D_) row[h] = skl_emd[s * D_ + h];
  __syncthreads();
  float acc = 0.f;
#pragma unroll
  for (int d = 0; d < D_; d++) acc += row[d] * U[h * D_ + d];
  sklproj[s * H_ + h] = acc;
}

// ---------------- Kernel B: att[p][k] = softmax_k( sum_h v[h]*tanh(projP[p][h]+sklproj[g[p][k]][h]) )
__global__ __launch_bounds__(128) void att_kernel(
    const float* __restrict__ plm_emd, const float* __restrict__ W,
    const float* __restrict__ vT, const float* __restrict__ sklproj,
    const int* __restrict__ gidx, float* __restrict__ att) {
  __shared__ float prow[D_];
  __shared__ float red[2][K_];
  const int p = blockIdx.x, h = threadIdx.x;
  if (h < D_) prow[h] = plm_emd[p * D_ + h];
  __syncthreads();
  float pp = 0.f;
#pragma unroll
  for (int d = 0; d < D_; d++) pp += prow[d] * W[h * D_ + d];
  const float v = vT[h];
  int g[K_];
#pragma unroll
  for (int k = 0; k < K_; k++) g[k] = gidx[p * K_ + k];
  float partial[K_];
#pragma unroll
  for (int k = 0; k < K_; k++) partial[k] = v * tanhf(pp + sklproj[g[k] * H_ + h]);
#pragma unroll
  for (int off = 32; off >= 1; off >>= 1)
#pragma unroll
    for (int k = 0; k < K_; k++) partial[k] += __shfl_down(partial[k], off, 64);
  const int wave = h >> 6, lane = h & 63;
  if (lane == 0)
#pragma unroll
    for (int k = 0; k < K_; k++) red[wave][k] = partial[k];
  __syncthreads();
  if (h == 0) {
    float s[K_], m = -1e30f;
#pragma unroll
    for (int k = 0; k < K_; k++) { s[k] = red[0][k] + red[1][k]; m = fmaxf(m, s[k]); }
    float denom = 0.f;
#pragma unroll
    for (int k = 0; k < K_; k++) { s[k] = expf(s[k] - m); denom += s[k]; }
    const float inv = 1.f / denom;
#pragma unroll
    for (int k = 0; k < K_; k++) att[p * K_ + k] = s[k] * inv;
  }
}

// ---------------- Kernel C: out[b][p] = mask[b][p] * sum_k skl_pfc[b][g[p][k]] * att[p][k]
// Each thread owns p = 4t..4t+3 (all of P in one pass) so mask / att / gidx / out are
// float4 (1 KB per wave-instr) instead of dword (256 B). All 8 mask float4 loads issue
// before the gather phase so they're in flight during LDS work. Gathers: bf16-packed
// transposed tile, one ds_read_b128 per (p,k) covers all 8 batch rows.
__global__ __launch_bounds__(256) void out_kernel(
    const float* __restrict__ skl_pfc, const float* __restrict__ mask,
    const float* __restrict__ att, const int* __restrict__ gidx,
    float* __restrict__ out) {
  __shared__ __align__(16) unsigned int rowsT[S_][4];  // 8192 B
  const int t = threadIdx.x;
  const int b0 = blockIdx.x * BT;

  // stage transposed + bf16-pack: s = t, t+256; coalesced reads across lanes per bb
#pragma unroll
  for (int i = 0; i < S_ / 256; i++) {
    const int s = t + i * 256;
    unsigned int pk[4];
#pragma unroll
    for (int q = 0; q < 4; q++) {
      const float f0 = skl_pfc[(size_t)(b0 + 2 * q) * S_ + s];
      const float f1 = skl_pfc[(size_t)(b0 + 2 * q + 1) * S_ + s];
      pk[q] = rne16(f0) | (rne16(f1) << 16);
    }
    *(uint4*)&rowsT[s][0] = make_uint4(pk[0], pk[1], pk[2], pk[3]);
  }

  const int p0 = t * 4;
  // prefetch all 8 mask rows as float4 (in flight across the gather phase)
  float4 mk[BT];
#pragma unroll
  for (int bb = 0; bb < BT; bb++)
    mk[bb] = *(const float4*)(mask + (size_t)(b0 + bb) * P_ + p0);

  __syncthreads();

  float acc[4][BT];
#pragma unroll
  for (int pp = 0; pp < 4; pp++) {
    const int p = p0 + pp;
    const float4* ap = (const float4*)(att + (size_t)p * K_);
    const int4* gp = (const int4*)(gidx + (size_t)p * K_);
    const float4 a0 = ap[0], a1 = ap[1];
    const int4 g0 = gp[0], g1 = gp[1];
    const float av[K_] = {a0.x, a0.y, a0.z, a0.w, a1.x, a1.y, a1.z, a1.w};
    const int gv[K_] = {g0.x, g0.y, g0.z, g0.w, g1.x, g1.y, g1.z, g1.w};
    float a[BT] = {0.f, 0.f, 0.f, 0.f, 0.f, 0.f, 0.f, 0.f};
#pragma unroll
    for (int k = 0; k < K_; k++) {
      const uint4 q0 = *(const uint4*)&rowsT[gv[k]][0];  // bb 0..7 packed bf16
      const float w = av[k];
      a[0] += bflo(q0.x) * w; a[1] += bfhi(q0.x) * w;
      a[2] += bflo(q0.y) * w; a[3] += bfhi(q0.y) * w;
      a[4] += bflo(q0.z) * w; a[5] += bfhi(q0.z) * w;
      a[6] += bflo(q0.w) * w; a[7] += bfhi(q0.w) * w;
    }
#pragma unroll
    for (int bb = 0; bb < BT; bb++) acc[pp][bb] = a[bb];
  }

  // float4 stores over the p-dimension
#pragma unroll
  for (int bb = 0; bb < BT; bb++) {
    float4 o;
    o.x = acc[0][bb] * mk[bb].x;
    o.y = acc[1][bb] * mk[bb].y;
    o.z = acc[2][bb] * mk[bb].z;
    o.w = acc[3][bb] * mk[bb].w;
    *(float4*)(out + (size_t)(b0 + bb) * P_ + p0) = o;
  }
}

extern "C" void kernel_launch(void* const* d_in, const int* in_sizes, int n_in,
                              void* d_out, int out_size, void* d_ws, size_t ws_size,
                              hipStream_t stream) {
  const float* skl_pfc = (const float*)d_in[0];   // [B, S]
  const float* mask    = (const float*)d_in[1];   // [B, P]
  const float* skl_emd = (const float*)d_in[2];   // [S, D]
  const float* plm_emd = (const float*)d_in[3];   // [P, D]
  const float* W       = (const float*)d_in[4];   // [H, D]
  const float* U       = (const float*)d_in[5];   // [H, D]
  const float* vT      = (const float*)d_in[6];   // [1, H]
  const int*   gidx    = (const int*)d_in[7];     // [P, K]
  float* out = (float*)d_out;                     // [B, P]

  float* sklproj = (float*)d_ws;                  // S*H floats = 256 KB
  float* att     = sklproj + S_ * H_;             // P*K floats = 32 KB

  proj_skl_kernel<<<S_, 128, 0, stream>>>(skl_emd, U, sklproj);
  att_kernel<<<P_, 128, 0, stream>>>(plm_emd, W, vT, sklproj, gidx, att);
  out_kernel<<<B_ / BT, 256, 0, stream>>>(skl_pfc, mask, att, gidx, out);
}